// Round 16
// baseline (506.048 us; speedup 1.0000x reference)
//
#include <hip/hip_runtime.h>
#include <hip/hip_bf16.h>

// VectorQuantizer B=32768, K=4096, D=512, fp32 in/out.
// Out concat (f32): quantized_st[B*512] | indices[B] | loss | perplexity | encodings[B*4096].
// R16: A-resident / B-streamed screen. 128 rows/block (afrag[2][16] in VGPRs,
// loaded once); B = 128 x 32-col full-K tiles (32KB) double-buffered in LDS with
// counted vmcnt(8) + raw s_barrier (loads never drained); 64 MFMA per wave per
// tile with B-frags shared across both row-frags (LDS traffic <= MFMA time).
// Per-c-class top-3 candidates (32-entry partials); numpy-fp32 rescore verbatim.

typedef __attribute__((ext_vector_type(8))) short bf16x8;
typedef __attribute__((ext_vector_type(4))) float f32x4;

#define BB 32768
#define KK 4096
#define DD 512

#define IDX_OFF  (BB*DD)
#define LOSS_OFF (IDX_OFF + BB)
#define PERP_OFF (LOSS_OFF + 1)
#define ENC_OFF  (PERP_OFF + 1)

// ws byte offsets
#define WSB_XSQ  0
#define WSB_ESQ  131072
#define WSB_IDX  147456
#define WSB_HIST 278528
#define WSB_LOSS 294912
#define WSB_EBF  294928          // 4 MB: E bf16, 128 chunks of 32 cols x 512 K (32KB)
#define WSB_XBF  4489232         // 32 MB: X bf16, k-slice-major (R15 layout)
#define WSB_PART 38043664        // 8 MB: uint2 partials [32][32768]

#define MARG 2.5e-4f
#define NCAND 16

static __device__ __forceinline__ unsigned short f2bf(float f) {
    __hip_bfloat16 h = __float2bfloat16(f);
    return *reinterpret_cast<unsigned short*>(&h);
}

static __device__ __forceinline__ unsigned int packscore(float s, int col) {
    unsigned int u = __float_as_uint(s);
    u ^= (u & 0x80000000u) ? 0xFFFFFFFFu : 0x80000000u;
    return (u & 0xFFFFF000u) | (unsigned int)col;
}
static __device__ __forceinline__ float unpackscore(unsigned int p) {
    unsigned int u = p & 0xFFFFF000u;
    u = (u & 0x80000000u) ? (u ^ 0x80000000u) : ~u;
    return __uint_as_float(u);
}

static __device__ __forceinline__ void gll16(const void* g, void* l) {
    __builtin_amdgcn_global_load_lds(
        (const __attribute__((address_space(1))) unsigned int*)g,
        (__attribute__((address_space(3))) unsigned int*)l, 16, 0, 0);
}

// numpy-emulated row sum-of-squares (tree bit-identical R5-R15) fused with X packing
// (k-slice-major: chunk(row>>8,kt)*2048 + (ks*16+rf)*64 + oct*16 + (row&15)).
__global__ __launch_bounds__(256) void npsum_pack_kernel(const float* __restrict__ X,
                                                         const float* __restrict__ E,
                                                         float* __restrict__ xsq,
                                                         float* __restrict__ esq,
                                                         unsigned short* __restrict__ Xbf) {
    __shared__ float sq[4][512];
    __shared__ float ub[4][64];
    __shared__ float bb[4][4];
    int w = threadIdx.x >> 6, lane = threadIdx.x & 63;
    int row = blockIdx.x * 4 + w;
    const float* src; float* dst;
    bool isx = (row < BB);
    if (isx) { src = X + (size_t)row * DD;        dst = xsq + row; }
    else     { src = E + (size_t)(row - BB) * DD; dst = esq + (row - BB); }
    const float4* s4 = (const float4*)(src + lane * 8);
    float4 a = s4[0], b = s4[1];
    sq[w][lane * 8 + 0] = __fmul_rn(a.x, a.x);
    sq[w][lane * 8 + 1] = __fmul_rn(a.y, a.y);
    sq[w][lane * 8 + 2] = __fmul_rn(a.z, a.z);
    sq[w][lane * 8 + 3] = __fmul_rn(a.w, a.w);
    sq[w][lane * 8 + 4] = __fmul_rn(b.x, b.x);
    sq[w][lane * 8 + 5] = __fmul_rn(b.y, b.y);
    sq[w][lane * 8 + 6] = __fmul_rn(b.z, b.z);
    sq[w][lane * 8 + 7] = __fmul_rn(b.w, b.w);
    if (isx) {
        int kt64 = lane >> 3, ks = (lane >> 2) & 1, oct = lane & 3;
        int rf = (row >> 4) & 15;
        size_t unit = ((size_t)((row >> 8) * 8 + kt64)) * 2048
                    + (size_t)((ks * 16 + rf) * 64 + oct * 16 + (row & 15));
        union { bf16x8 v; unsigned short us[8]; } pk;
        pk.us[0] = f2bf(a.x); pk.us[1] = f2bf(a.y); pk.us[2] = f2bf(a.z); pk.us[3] = f2bf(a.w);
        pk.us[4] = f2bf(b.x); pk.us[5] = f2bf(b.y); pk.us[6] = f2bf(b.z); pk.us[7] = f2bf(b.w);
        *(bf16x8*)(Xbf + unit * 8) = pk.v;
    }
    __syncthreads();
    {
        int b2 = lane >> 4, l = lane & 15;
        const float* s = &sq[w][b2 * 128];
        float t = __fadd_rn(
            __fadd_rn(__fadd_rn(s[l], s[16 + l]), __fadd_rn(s[32 + l], s[48 + l])),
            __fadd_rn(__fadd_rn(s[64 + l], s[80 + l]), __fadd_rn(s[96 + l], s[112 + l])));
        ub[w][lane] = t;
    }
    __syncthreads();
    if (lane < 4) {
        const float* u = &ub[w][lane * 16];
        float T3[8], T6[4];
        #pragma unroll
        for (int i = 0; i < 8; ++i) T3[i] = __fadd_rn(u[i], u[i + 8]);
        #pragma unroll
        for (int i = 0; i < 4; ++i) T6[i] = __fadd_rn(T3[i], T3[i + 4]);
        bb[w][lane] = __fadd_rn(__fadd_rn(T6[0], T6[2]), __fadd_rn(T6[1], T6[3]));
    }
    __syncthreads();
    if (lane == 0)
        *dst = __fadd_rn(__fadd_rn(bb[w][0], bb[w][1]), __fadd_rn(bb[w][2], bb[w][3]));
}

// E fp32 -> bf16, 128 chunks of 32 cols x full K (32KB). Unit u=(ks*2+nf)*64+lane
// holds E[chunk*32+nf*16+(lane&15)][ks*32+(lane>>4)*8 ..+7]. Fused hist/loss init.
__global__ __launch_bounds__(256) void packE_kernel(const float* __restrict__ E,
                                                    unsigned short* __restrict__ Ebf,
                                                    int* __restrict__ hist,
                                                    double* __restrict__ loss_acc) {
    int t = blockIdx.x * 256 + threadIdx.x;     // 262144 units, grid 1024
    if (t < KK) hist[t] = 0;
    if (t == KK) *loss_acc = 0.0;
    int chunk = t >> 11, u = t & 2047;
    int ks = u >> 7, nf = (u >> 6) & 1, lane = u & 63;
    int col = chunk * 32 + nf * 16 + (lane & 15);
    int k   = ks * 32 + (lane >> 4) * 8;
    const float4* s = (const float4*)(E + (size_t)col * DD + k);
    float4 a = s[0], b = s[1];
    union { bf16x8 v; unsigned short us[8]; } pk;
    pk.us[0] = f2bf(a.x); pk.us[1] = f2bf(a.y); pk.us[2] = f2bf(a.z); pk.us[3] = f2bf(a.w);
    pk.us[4] = f2bf(b.x); pk.us[5] = f2bf(b.y); pk.us[6] = f2bf(b.z); pk.us[7] = f2bf(b.w);
    *(bf16x8*)(Ebf + (size_t)t * 8) = pk.v;
}

// Screen: grid 256 (1 block/CU), 256 thr (4 waves x 2 rowfrags = 128 rows).
// Dyn LDS 80KB: B dbuf 2x32KB + esq 16KB. Counted vmcnt(8), raw barriers.
__global__ __launch_bounds__(256, 1) void gemm_screen(
    const unsigned short* __restrict__ Xbf, const unsigned short* __restrict__ Ebf,
    const float* __restrict__ esqw, uint2* __restrict__ partials)
{
    extern __shared__ __align__(16) char pool[];
    float* esh = (float*)(pool + 65536);

    const int tid = threadIdx.x;
    const int w = tid >> 6, lane = tid & 63;
    const int c = lane & 15, g = lane >> 4;
    const int bid = blockIdx.x;
    const int orig = (bid & 7) * 32 + (bid >> 3);   // bijective: 256 % 8 == 0
    const int row0 = orig * 128;

    // esq -> LDS (read-only cache), then full sync before issuing async loads
    {
        const float4* s = (const float4*)esqw;
        float4* d = (float4*)esh;
        #pragma unroll
        for (int j = 0; j < 4; ++j) d[tid + j * 256] = s[tid + j * 256];
    }
    __syncthreads();

    // A-frags, loaded once: wave w -> local rowfrags {w*2, w*2+1}
    const char* Xc = (const char*)Xbf + (size_t)(orig >> 1) * 262144;
    const int rfb = (orig & 1) * 8 + w * 2;
    bf16x8 af0[16], af1[16];
    #pragma unroll
    for (int kg = 0; kg < 16; ++kg) {
        int kt = kg >> 1, ks2 = kg & 1;
        const char* base = Xc + (size_t)kt * 32768;
        af0[kg] = *(const bf16x8*)(base + (size_t)(((ks2 * 16 + rfb + 0) * 64) + lane) * 16);
        af1[kg] = *(const bf16x8*)(base + (size_t)(((ks2 * 16 + rfb + 1) * 64) + lane) * 16);
    }

    const char* Ec = (const char*)Ebf;
    #define ISSUE(t_) { \
        const char* s_ = Ec + (size_t)(t_) * 32768 + (size_t)tid * 16; \
        char* d_ = pool + ((t_) & 1) * 32768 + w * 1024; \
        gll16(s_,          d_); \
        gll16(s_ + 4096,   d_ + 4096); \
        gll16(s_ + 8192,   d_ + 8192); \
        gll16(s_ + 12288,  d_ + 12288); \
        gll16(s_ + 16384,  d_ + 16384); \
        gll16(s_ + 20480,  d_ + 20480); \
        gll16(s_ + 24576,  d_ + 24576); \
        gll16(s_ + 28672,  d_ + 28672); }

    unsigned int p1[2][4], p2[2][4], p3[2][4];
    #pragma unroll
    for (int i = 0; i < 2; ++i)
        #pragma unroll
        for (int r = 0; r < 4; ++r) { p1[i][r] = ~0u; p2[i][r] = ~0u; p3[i][r] = ~0u; }

    ISSUE(0); ISSUE(1);

    #define TOP3(i_, r_, q_) { \
        if ((q_) < p1[i_][r_]) { p3[i_][r_] = p2[i_][r_]; p2[i_][r_] = p1[i_][r_]; p1[i_][r_] = (q_); } \
        else if ((q_) < p2[i_][r_]) { p3[i_][r_] = p2[i_][r_]; p2[i_][r_] = (q_); } \
        else if ((q_) < p3[i_][r_]) { p3[i_][r_] = (q_); } }

    #define BODY(t_, WAITS_) { \
        asm volatile(WAITS_ ::: "memory"); \
        __builtin_amdgcn_s_barrier(); \
        __builtin_amdgcn_sched_barrier(0); \
        const char* Bp_ = pool + ((t_) & 1) * 32768; \
        f32x4 a00 = (f32x4){0.f,0.f,0.f,0.f}, a01 = (f32x4){0.f,0.f,0.f,0.f}; \
        f32x4 a10 = (f32x4){0.f,0.f,0.f,0.f}, a11 = (f32x4){0.f,0.f,0.f,0.f}; \
        __builtin_amdgcn_s_setprio(1); \
        _Pragma("unroll") for (int ks = 0; ks < 16; ++ks) { \
            bf16x8 b0 = *(const bf16x8*)(Bp_ + (((ks * 2 + 0) * 64) + lane) * 16); \
            bf16x8 b1 = *(const bf16x8*)(Bp_ + (((ks * 2 + 1) * 64) + lane) * 16); \
            a00 = __builtin_amdgcn_mfma_f32_16x16x32_bf16(af0[ks], b0, a00, 0, 0, 0); \
            a01 = __builtin_amdgcn_mfma_f32_16x16x32_bf16(af0[ks], b1, a01, 0, 0, 0); \
            a10 = __builtin_amdgcn_mfma_f32_16x16x32_bf16(af1[ks], b0, a10, 0, 0, 0); \
            a11 = __builtin_amdgcn_mfma_f32_16x16x32_bf16(af1[ks], b1, a11, 0, 0, 0); \
        } \
        __builtin_amdgcn_s_setprio(0); \
        { const int colb_ = (t_) * 32; \
          float e0_ = esh[colb_ + c], e1_ = esh[colb_ + 16 + c]; \
          unsigned int cl0_ = (unsigned int)(colb_ + c), cl1_ = (unsigned int)(colb_ + 16 + c); \
          _Pragma("unroll") for (int r = 0; r < 4; ++r) { \
              unsigned int q_; \
              q_ = packscore(fmaf(-2.0f, a00[r], e0_), cl0_); TOP3(0, r, q_); \
              q_ = packscore(fmaf(-2.0f, a01[r], e1_), cl1_); TOP3(0, r, q_); \
              q_ = packscore(fmaf(-2.0f, a10[r], e0_), cl0_); TOP3(1, r, q_); \
              q_ = packscore(fmaf(-2.0f, a11[r], e1_), cl1_); TOP3(1, r, q_); \
          } } \
        __builtin_amdgcn_s_barrier(); \
        __builtin_amdgcn_sched_barrier(0); \
        if ((t_) < 126) ISSUE((t_) + 2); }

    BODY(0, "s_waitcnt vmcnt(8)");
    #pragma unroll 2
    for (int t = 1; t <= 126; ++t) BODY(t, "s_waitcnt vmcnt(8)");
    BODY(127, "s_waitcnt vmcnt(0)");
    #undef BODY
    #undef TOP3
    #undef ISSUE

    // partials: 32 entries/row = per-c-class top-3 (+ sentinel pad)
    #pragma unroll
    for (int i = 0; i < 2; ++i) {
        #pragma unroll
        for (int r = 0; r < 4; ++r) {
            int row = row0 + w * 32 + i * 16 + g * 4 + r;
            partials[(size_t)(c * 2 + 0) * BB + row] = make_uint2(p1[i][r], p2[i][r]);
            partials[(size_t)(c * 2 + 1) * BB + row] = make_uint2(p3[i][r], 0xFFFFFFFFu);
        }
    }
}

// merge 32 partials -> candidates -> numpy-fp32 rescore (verbatim R5-R15)
__global__ __launch_bounds__(256) void reduce_kernel(
    const float* __restrict__ X, const float* __restrict__ E,
    const float* __restrict__ xsqw, const float* __restrict__ esqw,
    const uint2* __restrict__ partials, int* __restrict__ idxbuf,
    int* __restrict__ hist, double* __restrict__ loss_acc,
    float* __restrict__ out)
{
    __shared__ double lred[256];
    const int row = blockIdx.x * 256 + threadIdx.x;
    unsigned int m = 0xFFFFFFFFu;
    for (int e = 0; e < 32; ++e) m = min(m, partials[(size_t)e * BB + row].x);
    float lim = unpackscore(m) + MARG;
    int cand[NCAND]; int nc = 0;
    for (int e = 0; e < 32; ++e) {
        uint2 p = partials[(size_t)e * BB + row];
        if (unpackscore(p.x) <= lim && nc < NCAND) cand[nc++] = (int)(p.x & 0xFFFu);
        if (unpackscore(p.y) <= lim && nc < NCAND) cand[nc++] = (int)(p.y & 0xFFFu);
    }
    const float* xr = X + (size_t)row * DD;
    float xs = xsqw[row];
    float bd = 3.0e38f; int bk = 0x7fffffff;
    for (int cidx = 0; cidx < nc; ++cidx) {
        int k = cand[cidx] & (KK - 1);
        const float* er = E + (size_t)k * DD;
        float q1 = 0.f, q2 = 0.f;
        for (int d = 0; d < 384; ++d)   q1 = fmaf(xr[d], er[d], q1);
        for (int d = 384; d < 512; ++d) q2 = fmaf(xr[d], er[d], q2);
        float dot = __fadd_rn(q1, q2);
        float t1  = __fadd_rn(xs, esqw[k]);
        float dnp = __fsub_rn(t1, __fmul_rn(2.0f, dot));
        if (dnp < bd || (dnp == bd && k < bk)) { bd = dnp; bk = k; }
    }
    const float* er = E + (size_t)bk * DD;
    double ls = 0.0;
    for (int d = 0; d < DD; ++d) {
        double df = (double)xr[d] - (double)er[d];
        ls = fma(df, df, ls);
    }
    idxbuf[row] = bk;
    out[IDX_OFF + row] = (float)bk;
    atomicAdd(&hist[bk], 1);
    lred[threadIdx.x] = ls;
    __syncthreads();
    for (int t = 128; t > 0; t >>= 1) {
        if (threadIdx.x < t) lred[threadIdx.x] += lred[threadIdx.x + t];
        __syncthreads();
    }
    if (threadIdx.x == 0) atomicAdd(loss_acc, lred[0]);
}

// one block per row: quantized gather (coalesced) + one-hot row
__global__ __launch_bounds__(256) void encq_kernel(const int* __restrict__ idxbuf,
                                                   const float* __restrict__ E,
                                                   float* __restrict__ out) {
    int row = blockIdx.x;
    int idx = idxbuf[row];
    ((float2*)out)[(size_t)row * 256 + threadIdx.x] =
        ((const float2*)E)[(size_t)idx * 256 + threadIdx.x];
    float2* erow = (float2*)(out + ENC_OFF) + (size_t)row * (KK / 2);
    int half = idx >> 1;
    float2 one;
    if (idx & 1) { one.x = 0.f; one.y = 1.f; } else { one.x = 1.f; one.y = 0.f; }
    float2 z; z.x = 0.f; z.y = 0.f;
    for (int cc = threadIdx.x; cc < KK / 2; cc += 256)
        erow[cc] = (cc == half) ? one : z;
}

__global__ __launch_bounds__(256) void fin_kernel(const int* __restrict__ hist,
                                                  const double* __restrict__ loss_acc,
                                                  float* __restrict__ out) {
    __shared__ double red[256];
    int tid = threadIdx.x;
    double s = 0.0;
    for (int k = tid; k < KK; k += 256) {
        double p = (double)hist[k] * (1.0 / 32768.0);
        s += p * log(p + 1e-10);
    }
    red[tid] = s;
    __syncthreads();
    for (int t = 128; t > 0; t >>= 1) {
        if (tid < t) red[tid] += red[tid + t];
        __syncthreads();
    }
    if (tid == 0) {
        double perp = exp(-red[0]);
        double L = loss_acc[0] * (1.0 / ((double)BB * (double)DD));
        out[LOSS_OFF] = (float)(1.25 * L);
        out[PERP_OFF] = (float)perp;
    }
}

extern "C" void kernel_launch(void* const* d_in, const int* in_sizes, int n_in,
                              void* d_out, int out_size, void* d_ws, size_t ws_size,
                              hipStream_t stream) {
    const float* X; const float* E;
    if (in_sizes[0] == BB * DD) { X = (const float*)d_in[0]; E = (const float*)d_in[1]; }
    else                        { X = (const float*)d_in[1]; E = (const float*)d_in[0]; }
    float* out = (float*)d_out;

    float* xsq = (float*)((char*)d_ws + WSB_XSQ);
    float* esq = (float*)((char*)d_ws + WSB_ESQ);
    int* idxbuf = (int*)((char*)d_ws + WSB_IDX);
    int* hist   = (int*)((char*)d_ws + WSB_HIST);
    double* loss_acc = (double*)((char*)d_ws + WSB_LOSS);
    unsigned short* Ebf = (unsigned short*)((char*)d_ws + WSB_EBF);
    unsigned short* Xbf = (unsigned short*)((char*)d_ws + WSB_XBF);
    uint2* partials = (uint2*)((char*)d_ws + WSB_PART);

    hipLaunchKernelGGL(npsum_pack_kernel, dim3((BB + KK) / 4), dim3(256), 0, stream,
                       X, E, xsq, esq, Xbf);
    hipLaunchKernelGGL(packE_kernel, dim3(1024), dim3(256), 0, stream,
                       E, Ebf, hist, loss_acc);
    hipLaunchKernelGGL(gemm_screen, dim3(256), dim3(256), 81920, stream,
                       Xbf, Ebf, esq, partials);
    hipLaunchKernelGGL(reduce_kernel, dim3(BB / 256), dim3(256), 0, stream,
                       X, E, xsq, esq, partials, idxbuf, hist, loss_acc, out);
    hipLaunchKernelGGL(encq_kernel, dim3(BB), dim3(256), 0, stream, idxbuf, E, out);
    hipLaunchKernelGGL(fin_kernel, dim3(1), dim3(256), 0, stream, hist, loss_acc, out);
}